// Round 10
// baseline (377.787 us; speedup 1.0000x reference)
//
#include <hip/hip_runtime.h>

typedef float v2f __attribute__((ext_vector_type(2)));

#define TY 8                  // output rows per chunk
#define WIN 18                // private ring rows (TY + 10)
#define CST 33                // col stride (32 cols + 1 pad)
#define RST (5 * CST)         // ring row stride = 165 dwords (165%32=5)
#define SWV (WIN * RST)       // per-wave ring = 2970 dwords = 11,880 B
#define IMW 512
#define IMH 512
#define NPLANES 96            // 32 * 3
#define NSX 16                // 32-col strips
#define NSEG 2                // 256-row segments
#define NCH 32                // chunks per segment (256/8)
#define NWAVES (NSX * NSEG * NPLANES)  // 3072
#define NBLOCKS (NWAVES / 4)           // 768 = 3 blocks/CU, ALL resident

// Gaussian(sigma=1.5, ws=11), double-computed, fp32-rounded.
#define GW0 0.00102838f
#define GW1 0.00759877f
#define GW2 0.03600077f
#define GW3 0.10936069f
#define GW4 0.21300553f
#define GW5 0.26601172f

__device__ __forceinline__ void pkfma(v2f& acc, v2f a, v2f b) {
  asm("v_pk_fma_f32 %0, %1, %2, %0" : "+v"(acc) : "v"(a), "v"(b));
}
__device__ __forceinline__ v2f pkmul(v2f a, v2f b) {
  v2f d;
  asm("v_pk_mul_f32 %0, %1, %2" : "=v"(d) : "v"(a), "v"(b));
  return d;
}

// Register-staged raw window: 10 float4, accessed ONLY with compile-time
// indices (r2-proven pattern). Lifetime: loaded at end of loop iter c,
// consumed (transform+store) in iter c+1 AFTER vchunk -- loop-carried, so
// the compiler cannot sink the loads to the use; ~550 cyc of vchunk hides
// the HBM latency that capped round 9 at 57% VALUBusy.
struct Raw {
  float4 g[5];
  float4 r[5];
};

// Issue global loads for one h-row per lane: hr = lane>>3, xs = (lane&7)*4.
// Loads cover cols [xs-8, xs+12) of row gy0+hr.
__device__ __forceinline__ void hload(
    const float* __restrict__ gp, const float* __restrict__ rp,
    int x0, bool fast, int gy0, int hr, int xs, Raw& L) {
  const int gy = gy0 + hr;
  const int xbase = x0 + xs - 8;
  const float* grow = gp + (size_t)gy * IMW;
  const float* rrow = rp + (size_t)gy * IMW;
  if (fast) {
#pragma unroll
    for (int k = 0; k < 5; ++k) {
      L.g[k] = *(const float4*)(grow + xbase + 4 * k);
      L.r[k] = *(const float4*)(rrow + xbase + 4 * k);
    }
  } else {
    const bool rowok = (gy >= 0) & (gy < IMH);
#pragma unroll
    for (int k = 0; k < 5; ++k) {
      const int c = xbase + 4 * k;
      const bool ok = rowok && (c >= 0) && (c < IMW);
      float4 g4 = make_float4(-1.f, -1.f, -1.f, -1.f);
      float4 r4 = g4;  // transform maps -1 -> 0 (matches conv zero padding)
      if (ok) {
        g4 = *(const float4*)(grow + c);
        r4 = *(const float4*)(rrow + c);
      }
      L.g[k] = g4;
      L.r[k] = r4;
    }
  }
}

// Transform + horizontal 11-tap blur + ds_write of one staged row into the
// wave's private ring at slot0+hr. Window cols xs-5..xs+8 = P[0..13].
__device__ __forceinline__ void hstore(
    const Raw& L, float* __restrict__ sq, int slot0, int hr, int xs) {
  const float GW[11] = {GW0, GW1, GW2, GW3, GW4, GW5,
                        GW4, GW3, GW2, GW1, GW0};
  int slot = slot0 + hr;
  if (slot >= WIN) slot -= WIN;  // slot0<=16, hr<=7 -> one subtract

  v2f P[14];  // transformed (g,r); window position p <-> loaded col p+3
#define PUT1(idx, gc, rc)                                                    \
  do {                                                                       \
    if ((idx) >= 3 && (idx) <= 16)                                           \
      P[(idx) - 3] = (v2f){fmaf(0.5f, (gc), 0.5f), fmaf(0.5f, (rc), 0.5f)};  \
  } while (0)
#pragma unroll
  for (int k = 0; k < 5; ++k) {
    const float4 g4 = L.g[k];
    const float4 r4 = L.r[k];
    PUT1(4 * k + 0, g4.x, r4.x);
    PUT1(4 * k + 1, g4.y, r4.y);
    PUT1(4 * k + 2, g4.z, r4.z);
    PUT1(4 * k + 3, g4.w, r4.w);
  }
#undef PUT1

  v2f accP[4], accQ[4];
  float accS[4];
#pragma unroll
  for (int o = 0; o < 4; ++o) {
    accP[o] = (v2f){0.f, 0.f};
    accQ[o] = (v2f){0.f, 0.f};
    accS[o] = 0.f;
  }

  // Output o (col xs+o) uses window positions p = o..o+10.
#pragma unroll
  for (int p = 0; p < 14; ++p) {
    const v2f pv = P[p];
    const v2f qv = pkmul(pv, pv);
    const float sv = pv.x * pv.y;
    const int olo = (p - 10 < 0) ? 0 : p - 10;
    const int ohi = (p < 3) ? p : 3;
#pragma unroll
    for (int o = olo; o <= ohi; ++o) {
      const float wt = GW[p - o];
      const v2f wv = (v2f){wt, wt};
      pkfma(accP[o], wv, pv);
      pkfma(accQ[o], wv, qv);
      accS[o] = fmaf(wt, sv, accS[o]);
    }
  }

  // One VGPR address, planes via immediate dword offsets q*33+o (max 135
  // -> ds_write2_b32 pairs). Banks: (5*slot+4*cg+o) mod 32 over 8x8 lanes
  // -> exactly 2 lanes/bank (free, m136).
  float* dst = sq + slot * RST + xs;
#pragma unroll
  for (int o = 0; o < 4; ++o) dst[0 * CST + o] = accP[o].x;
#pragma unroll
  for (int o = 0; o < 4; ++o) dst[1 * CST + o] = accP[o].y;
#pragma unroll
  for (int o = 0; o < 4; ++o) dst[2 * CST + o] = accQ[o].x;
#pragma unroll
  for (int o = 0; o < 4; ++o) dst[3 * CST + o] = accQ[o].y;
#pragma unroll
  for (int o = 0; o < 4; ++o) dst[4 * CST + o] = accS[o];
}

// Fused load+store for the prologue only (latency exposed once per wave).
__device__ __forceinline__ void hblur(
    const float* __restrict__ gp, const float* __restrict__ rp,
    float* __restrict__ sq, int x0, bool fast, int nrows, int gy0,
    int slot0, int hr, int xs) {
  if (hr >= nrows) return;
  Raw t;
  hload(gp, rp, x0, fast, gy0, hr, xs, t);
  hstore(t, sq, slot0, hr, xs);
}

__device__ __forceinline__ float ssim_px(v2f mu, v2f ee, float e12) {
  const float C1 = 6.5025f, C2 = 58.5225f;
  const float mu1 = mu.x, mu2 = mu.y, e1 = ee.x, e2 = ee.y;
  const float m12 = mu1 * mu2;
  const float m1s = mu1 * mu1;
  const float m2s = mu2 * mu2;
  const float num = (2.f * m12 + C1) * (2.f * (e12 - m12) + C2);
  const float den = (m1s + m2s + C1) * ((e1 - m1s) + (e2 - m2s) + C2);
  return __fdividef(num, den);
}

// v-phase: vertical 11-tap blur + SSIM for 4 output rows per lane,
// streaming 14 ring rows. Lane role: col = lane&31, r0 = (lane>>5)*4.
// Read banks: 32 stride-1 cols x 2 groups -> exactly 2-way (free).
__device__ __forceinline__ float vchunk(
    const float* __restrict__ sq, int wb, int col, int r0) {
  const float GW[11] = {GW0, GW1, GW2, GW3, GW4, GW5,
                        GW4, GW3, GW2, GW1, GW0};
  v2f mu[4], ee[4];
  float e12[4];
#pragma unroll
  for (int o = 0; o < 4; ++o) {
    mu[o] = (v2f){0.f, 0.f};
    ee[o] = (v2f){0.f, 0.f};
    e12[o] = 0.f;
  }
#pragma unroll
  for (int i = 0; i < 14; ++i) {
    int slot = wb + r0 + i;        // <= 16+4+13 = 33
    if (slot >= WIN) slot -= WIN;  // one subtract suffices (< 2*WIN)
    const float* rowp = sq + slot * RST + col;
    const v2f hp = (v2f){rowp[0 * CST], rowp[1 * CST]};  // ds_read2_b32
    const v2f hq = (v2f){rowp[2 * CST], rowp[3 * CST]};  // ds_read2_b32
    const float hsv = rowp[4 * CST];
    const int olo = (i - 10 < 0) ? 0 : i - 10;
    const int ohi = (i < 3) ? i : 3;
#pragma unroll
    for (int o = olo; o <= ohi; ++o) {  // row i is tap i-o of output o
      const float wt = GW[i - o];
      const v2f wv = (v2f){wt, wt};
      pkfma(mu[o], wv, hp);
      pkfma(ee[o], wv, hq);
      e12[o] = fmaf(wt, hsv, e12[o]);
    }
  }
  return (ssim_px(mu[0], ee[0], e12[0]) + ssim_px(mu[1], ee[1], e12[1])) +
         (ssim_px(mu[2], ee[2], e12[2]) + ssim_px(mu[3], ee[3], e12[3]));
}

__global__ __launch_bounds__(256, 3) void ssim_main(
    const float* __restrict__ gen, const float* __restrict__ ref,
    double* __restrict__ partial) {
  // Wave-private tiles (r9) + in-wave software pipeline (r10):
  // each iter: vchunk(c) -> hstore(L -> ring, chunk c+1) -> hload(L, c+2).
  // Zero barriers; loads issued one full vchunk before their use.
  // launch_bounds(256,3): allocator budget ~170 VGPR; occupancy is
  // LDS-capped at 3 blocks/CU (12 waves) so VGPR<=128 costs nothing.
  __shared__ float ring[4][SWV];  // 47,520 B

  const int tid = threadIdx.x;
  const int wv = tid >> 6;
  const int lane = tid & 63;
  const int wid = (blockIdx.x << 2) | wv;
  const int plane = wid >> 5;        // 32 wave-tasks per plane
  const int rem = wid & 31;
  const int sx = rem & 15;
  const int seg = rem >> 4;
  const int x0 = sx * 32;
  const int Y0 = seg * 256;
  const float* gp = gen + (size_t)plane * (IMW * IMH);
  const float* rp = ref + (size_t)plane * (IMW * IMH);
  float* const sq = &ring[wv][0];
  const bool fx = (sx >= 1) & (sx <= NSX - 2);

  const int hr = lane >> 3;        // h-phase: row 0..7
  const int xs = (lane & 7) * 4;   // h-phase: 4-col run
  const int col = lane & 31;       // v-phase: column
  const int r0 = (lane >> 5) * 4;  // v-phase: first of 4 output rows

  // Prologue: fill ring with h-rows [Y0-5, Y0+13) -> slots 0..17.
  hblur(gp, rp, sq, x0, fx & (seg > 0), 8, Y0 - 5, 0, hr, xs);
  hblur(gp, rp, sq, x0, fx, 8, Y0 + 3, 8, hr, xs);
  hblur(gp, rp, sq, x0, fx, 2, Y0 + 11, 16, hr, xs);

  // Stage chunk 1's h-rows [Y0+13, +8) into registers.
  Raw L;
  hload(gp, rp, x0, fx, Y0 + 13, hr, xs, L);

  double acc = 0.0;
  int wb = 0;  // window base: (8c) mod 18
#pragma unroll 1
  for (int c = 0; c < NCH; ++c) {
    // Consume chunk c: output rows Y0+8c..+7 from ring window wb..wb+17.
    acc += (double)vchunk(sq, wb, col, r0);
    if (c < NCH - 1) {
      // Chunk c+1 (staged in L one vchunk ago): transform + blur + store
      // over the 8 oldest slots (base = wb). Same-wave DS order protects
      // the read-then-write overlap; no barrier.
      hstore(L, sq, wb, hr, xs);
      if (c < NCH - 2) {
        // Refill L with chunk c+2's h-rows [Y0+21+8c, +8); consumed after
        // the NEXT vchunk (the latency-hiding distance).
        const int gy0 = Y0 + 21 + TY * c;
        hload(gp, rp, x0, fx && (gy0 + TY <= IMH), gy0, hr, xs, L);
      }
    }
    wb += TY;
    if (wb >= WIN) wb -= WIN;
  }

  // Wave-level reduction only (waves never interact): one double per wave.
#pragma unroll
  for (int off = 32; off > 0; off >>= 1) acc += __shfl_down(acc, off, 64);
  if (lane == 0) partial[wid] = acc;
}

__global__ void ssim_reduce(const double* __restrict__ partial,
                            float* __restrict__ out) {
  const int tid = threadIdx.x;
  double s = 0.0;
  // 3072 = 12 * 256 partials, fixed-order per thread (deterministic).
  for (int i = tid; i < NWAVES; i += 256) s += partial[i];
#pragma unroll
  for (int off = 32; off > 0; off >>= 1) s += __shfl_down(s, off, 64);
  __shared__ double sd[4];
  if ((tid & 63) == 0) sd[tid >> 6] = s;
  __syncthreads();
  if (tid == 0) {
    const double npix = (double)NPLANES * (double)IMW * (double)IMH;
    out[0] = (float)(1.0 - (sd[0] + sd[1] + sd[2] + sd[3]) / npix);
  }
}

extern "C" void kernel_launch(void* const* d_in, const int* in_sizes, int n_in,
                              void* d_out, int out_size, void* d_ws, size_t ws_size,
                              hipStream_t stream) {
  (void)in_sizes; (void)n_in; (void)out_size; (void)ws_size;
  const float* gen = (const float*)d_in[0];
  const float* ref = (const float*)d_in[1];
  double* partial = (double*)d_ws;  // NWAVES doubles; every slot written each call
  ssim_main<<<NBLOCKS, 256, 0, stream>>>(gen, ref, partial);
  ssim_reduce<<<1, 256, 0, stream>>>(partial, (float*)d_out);
}